// Round 1
// baseline (403.159 us; speedup 1.0000x reference)
//
#include <hip/hip_runtime.h>
#include <stdint.h>

#define B_ 8
#define N_ 2048
#define D_ 120
#define DP 128          // D padded to 128 (k-dim of MFMA)
#define QB 32           // q rows per block in attention kernel

typedef __attribute__((ext_vector_type(8))) short short8;
typedef __attribute__((ext_vector_type(4))) float f32x4;
typedef unsigned short u16;

// f32 -> bf16 (RNE) and back, bit-level (all values finite here)
__device__ __forceinline__ u16 f2bf(float f){
    union { float f; uint32_t u; } v; v.f = f;
    uint32_t u = v.u;
    return (u16)((u + 0x7fffu + ((u >> 16) & 1u)) >> 16);
}
__device__ __forceinline__ float bf2f(u16 h){
    union { uint32_t u; float f; } v; v.u = ((uint32_t)h) << 16; return v.f;
}

__device__ __forceinline__ f32x4 mfma16(short8 a, short8 b, f32x4 c){
    return __builtin_amdgcn_mfma_f32_16x16x32_bf16(a, b, c, 0, 0, 0);
}

// ---------------------------------------------------------------------------
// Kernel 0: transpose + split weights. Wt[c][d] (bf16 hi/lo), zero-padded to
// 128x128. Scale 1/sqrt(D) folded into W_query.
// ---------------------------------------------------------------------------
__global__ void wprep(const float* __restrict__ Wq, const float* __restrict__ Wk,
                      const float* __restrict__ Wv,
                      u16* __restrict__ Wth, u16* __restrict__ Wtl){
    int p = blockIdx.x;
    const float* W = (p == 0) ? Wq : (p == 1 ? Wk : Wv);
    float scale = (p == 0) ? 0.09128709291752768f : 1.0f;  // 1/sqrt(120)
    for (int idx = threadIdx.x; idx < DP * DP; idx += blockDim.x){
        int c = idx & (DP - 1);
        int d = idx >> 7;
        float w = (c < D_ && d < D_) ? W[d * D_ + c] * scale : 0.f;
        u16 hi = f2bf(w);
        Wth[p * DP * DP + c * DP + d] = hi;
        Wtl[p * DP * DP + c * DP + d] = f2bf(w - bf2f(hi));
    }
}

// ---------------------------------------------------------------------------
// Kernel 1: projections via 3-term split-bf16 MFMA.
//   p=0: Q = (x1 @ Wq)*scale -> Qh/Ql  [16384][128] bf16
//   p=1: K =  x2 @ Wk        -> Kh/Kl  [16384][128] bf16
//   p=2: V =  x2 @ Wv        -> Vt     [8][128][2048] bf16 (transposed)
// Block: 256 threads (4 waves), each wave a 16-row tile; 64 rows per block.
// ---------------------------------------------------------------------------
__global__ __launch_bounds__(256, 4)
void proj_kernel(const float* __restrict__ x1, const float* __restrict__ x2,
                 const u16* __restrict__ Wth, const u16* __restrict__ Wtl,
                 u16* __restrict__ Qh, u16* __restrict__ Ql,
                 u16* __restrict__ Kh, u16* __restrict__ Kl,
                 u16* __restrict__ Vt){
    int p    = blockIdx.y;
    const float* x = (p == 0) ? x1 : x2;
    int wave = threadIdx.x >> 6, lane = threadIdx.x & 63;
    int g = lane >> 4, ln = lane & 15;
    long arow = (long)blockIdx.x * 64 + wave * 16 + ln;     // A row (M index)

    // A fragments: lane holds row (lane&15), k = 8*(lane>>4)+j
    short8 ah[4], al[4];
    #pragma unroll
    for (int ks = 0; ks < 4; ++ks){
        float xv[8];
        #pragma unroll
        for (int j = 0; j < 8; ++j){
            int d = ks * 32 + g * 8 + j;
            xv[j] = (d < D_) ? x[arow * D_ + d] : 0.f;
        }
        short8 h, l;
        #pragma unroll
        for (int j = 0; j < 8; ++j){
            u16 hb = f2bf(xv[j]);
            h[j] = (short)hb;
            l[j] = (short)f2bf(xv[j] - bf2f(hb));
        }
        ah[ks] = h; al[ks] = l;
    }

    const u16* wh = Wth + p * DP * DP;
    const u16* wl = Wtl + p * DP * DP;
    f32x4 acc[8];
    #pragma unroll
    for (int cf = 0; cf < 8; ++cf){
        f32x4 a = {0.f, 0.f, 0.f, 0.f};
        #pragma unroll
        for (int ks = 0; ks < 4; ++ks){
            short8 bh = *(const short8*)(wh + (cf * 16 + ln) * DP + ks * 32 + g * 8);
            short8 bl = *(const short8*)(wl + (cf * 16 + ln) * DP + ks * 32 + g * 8);
            a = mfma16(ah[ks], bh, a);
            a = mfma16(ah[ks], bl, a);
            a = mfma16(al[ks], bh, a);
        }
        acc[cf] = a;
    }

    // C/D layout: col = lane&15, row = 4*(lane>>4)+i
    #pragma unroll
    for (int cf = 0; cf < 8; ++cf){
        #pragma unroll
        for (int i = 0; i < 4; ++i){
            long orow = (long)blockIdx.x * 64 + wave * 16 + g * 4 + i;
            int  c    = cf * 16 + ln;
            float v   = acc[cf][i];
            if (p == 0){
                u16 hb = f2bf(v);
                Qh[orow * DP + c] = hb;
                Ql[orow * DP + c] = f2bf(v - bf2f(hb));
            } else if (p == 1){
                u16 hb = f2bf(v);
                Kh[orow * DP + c] = hb;
                Kl[orow * DP + c] = f2bf(v - bf2f(hb));
            } else {
                long bb = orow >> 11, n = orow & 2047;
                Vt[(bb * DP + c) * N_ + n] = f2bf(v);
            }
        }
    }
}

// ---------------------------------------------------------------------------
// Kernel 2: fused scores + softmax + attn-weight store + PV.
// Grid (64, 8): block = (batch, 32 q-rows). 8 waves: rt = wave>>2 selects the
// 16-row half, wc = wave&3 selects a 512-wide m slice. Each wave holds its
// 16x512 score slice in VGPRs (32 x f32x4 = 128 VGPR).
// ---------------------------------------------------------------------------
__global__ __launch_bounds__(512, 2)
void attn_kernel(const u16* __restrict__ Qh, const u16* __restrict__ Ql,
                 const u16* __restrict__ Kh, const u16* __restrict__ Kl,
                 const u16* __restrict__ Vt, const int* __restrict__ mask,
                 float* __restrict__ outp, float* __restrict__ attnw){
    __shared__ float outred[4 * 16 * 128];   // 32 KB: PV cross-wave reduce
    __shared__ float redm[2 * 4 * 16];       // row-max partials
    __shared__ float redsum_[2 * 4 * 16];    // row-sum partials

    int b  = blockIdx.y;
    int q0 = blockIdx.x * QB;
    int wave = threadIdx.x >> 6, lane = threadIdx.x & 63;
    int rt = wave >> 2, wc = wave & 3;
    int g  = lane >> 4, ln = lane & 15;

    long qbase = (long)b * N_ + q0 + rt * 16;   // global row of this 16-row tile

    // Q A-fragments (hoisted for all 4 k-steps, hi+lo)
    short8 ah[4], al[4];
    #pragma unroll
    for (int ks = 0; ks < 4; ++ks){
        ah[ks] = *(const short8*)(Qh + (qbase + ln) * DP + ks * 32 + g * 8);
        al[ks] = *(const short8*)(Ql + (qbase + ln) * DP + ks * 32 + g * 8);
    }

    // ---- scores: S = Qs @ K^T (3-term split) ----
    f32x4 sc[32];
    #pragma unroll
    for (int cf = 0; cf < 32; ++cf){
        int m0 = wc * 512 + cf * 16;
        const u16* kh = Kh + ((long)b * N_ + m0 + ln) * DP;
        const u16* kl = Kl + ((long)b * N_ + m0 + ln) * DP;
        f32x4 a = {0.f, 0.f, 0.f, 0.f};
        #pragma unroll
        for (int ks = 0; ks < 4; ++ks){
            short8 bh = *(const short8*)(kh + ks * 32 + g * 8);
            short8 bl = *(const short8*)(kl + ks * 32 + g * 8);
            a = mfma16(ah[ks], bh, a);
            a = mfma16(ah[ks], bl, a);
            a = mfma16(al[ks], bh, a);
        }
        sc[cf] = a;
    }

    // ---- mask ----
    #pragma unroll
    for (int cf = 0; cf < 32; ++cf){
        int m = wc * 512 + cf * 16 + ln;
        #pragma unroll
        for (int i = 0; i < 4; ++i){
            long r = qbase + g * 4 + i;
            if (mask[r * N_ + m] == 0) sc[cf][i] = -__builtin_inff();
        }
    }

    // ---- row max (in-wave slice, then cross the 4 column waves) ----
    float mx[4];
    #pragma unroll
    for (int i = 0; i < 4; ++i){
        float m = sc[0][i];
        #pragma unroll
        for (int cf = 1; cf < 32; ++cf) m = fmaxf(m, sc[cf][i]);
        #pragma unroll
        for (int s = 1; s < 16; s <<= 1) m = fmaxf(m, __shfl_xor(m, s, 64));
        mx[i] = m;
    }
    if (ln == 0){
        #pragma unroll
        for (int i = 0; i < 4; ++i) redm[(rt * 4 + wc) * 16 + g * 4 + i] = mx[i];
    }
    __syncthreads();
    float fm[4];
    #pragma unroll
    for (int i = 0; i < 4; ++i){
        int r = g * 4 + i;
        float m = fmaxf(fmaxf(redm[(rt * 4 + 0) * 16 + r], redm[(rt * 4 + 1) * 16 + r]),
                        fmaxf(redm[(rt * 4 + 2) * 16 + r], redm[(rt * 4 + 3) * 16 + r]));
        fm[i] = m;
    }

    // ---- exp + row sum ----
    float sm[4] = {0.f, 0.f, 0.f, 0.f};
    #pragma unroll
    for (int cf = 0; cf < 32; ++cf){
        #pragma unroll
        for (int i = 0; i < 4; ++i){
            float e = __expf(sc[cf][i] - fm[i]);
            sc[cf][i] = e;
            sm[i] += e;
        }
    }
    #pragma unroll
    for (int i = 0; i < 4; ++i){
        float s = sm[i];
        #pragma unroll
        for (int sft = 1; sft < 16; sft <<= 1) s += __shfl_xor(s, sft, 64);
        sm[i] = s;
    }
    if (ln == 0){
        #pragma unroll
        for (int i = 0; i < 4; ++i) redsum_[(rt * 4 + wc) * 16 + g * 4 + i] = sm[i];
    }
    __syncthreads();
    float inv[4];
    #pragma unroll
    for (int i = 0; i < 4; ++i){
        int r = g * 4 + i;
        float s = redsum_[(rt * 4 + 0) * 16 + r] + redsum_[(rt * 4 + 1) * 16 + r]
                + redsum_[(rt * 4 + 2) * 16 + r] + redsum_[(rt * 4 + 3) * 16 + r];
        inv[i] = 1.f / s;
    }

    // ---- normalize + store attention weights (fp32, required output) ----
    #pragma unroll
    for (int cf = 0; cf < 32; ++cf){
        int m = wc * 512 + cf * 16 + ln;
        #pragma unroll
        for (int i = 0; i < 4; ++i){
            float w = sc[cf][i] * inv[i];
            attnw[(qbase + g * 4 + i) * N_ + m] = w;
        }
    }
    // wave re-reads its own weight region below (A-fragment layout); drain stores
    asm volatile("s_waitcnt vmcnt(0)" ::: "memory");

    // ---- PV: out += P @ V  (A = P from global re-read, B = Vt contiguous) ----
    f32x4 oacc[8];
    #pragma unroll
    for (int e = 0; e < 8; ++e) oacc[e] = (f32x4){0.f, 0.f, 0.f, 0.f};
    #pragma unroll
    for (int mc = 0; mc < 16; ++mc){
        int mbase = wc * 512 + mc * 32;
        const float* prow = attnw + (qbase + ln) * N_ + mbase + g * 8;
        f32x4 p0 = *(const f32x4*)prow;
        f32x4 p1 = *(const f32x4*)(prow + 4);
        short8 pa;
        #pragma unroll
        for (int j = 0; j < 4; ++j) pa[j]     = (short)f2bf(p0[j]);
        #pragma unroll
        for (int j = 0; j < 4; ++j) pa[4 + j] = (short)f2bf(p1[j]);
        #pragma unroll
        for (int e = 0; e < 8; ++e){
            short8 vb = *(const short8*)(Vt + ((long)b * DP + e * 16 + ln) * N_ + mbase + g * 8);
            oacc[e] = mfma16(pa, vb, oacc[e]);
        }
    }

    // ---- cross-wave reduce of PV partials (the 4 column waves per rt) ----
    for (int rr = 0; rr < 2; ++rr){
        __syncthreads();
        if (rt == rr){
            #pragma unroll
            for (int e = 0; e < 8; ++e){
                #pragma unroll
                for (int i = 0; i < 4; ++i)
                    outred[(wc * 16 + g * 4 + i) * 128 + e * 16 + ln] = oacc[e][i];
            }
        }
        __syncthreads();
        if (rt == rr){
            int t    = threadIdx.x & 255;   // 0..255 within this rt group
            int base = t * 8;               // 16 rows x 128 e = 2048 elems
            int row  = base >> 7;
            int e0   = base & 127;
            long orow = (long)b * N_ + q0 + rr * 16 + row;
            #pragma unroll
            for (int j = 0; j < 8; ++j){
                int e = e0 + j;
                float v = outred[(0 * 16 + row) * 128 + e] + outred[(1 * 16 + row) * 128 + e]
                        + outred[(2 * 16 + row) * 128 + e] + outred[(3 * 16 + row) * 128 + e];
                if (e < D_) outp[orow * D_ + e] = v;
            }
        }
    }
}

// ---------------------------------------------------------------------------
extern "C" void kernel_launch(void* const* d_in, const int* in_sizes, int n_in,
                              void* d_out, int out_size, void* d_ws, size_t ws_size,
                              hipStream_t stream){
    const float* x1   = (const float*)d_in[0];
    const float* x2   = (const float*)d_in[1];
    const int*   mask = (const int*)d_in[2];
    const float* Wq   = (const float*)d_in[3];
    const float* Wk   = (const float*)d_in[4];
    const float* Wv   = (const float*)d_in[5];

    float* outp  = (float*)d_out;
    float* attnw = outp + (size_t)B_ * N_ * D_;   // outputs concatenated flat

    // workspace carve (u16 elems): 5 x 4MB bf16 tensors + split weights
    const size_t TEN = (size_t)B_ * N_ * DP;      // 2,097,152
    u16* Qh  = (u16*)d_ws;
    u16* Ql  = Qh + TEN;
    u16* Kh  = Ql + TEN;
    u16* Kl  = Kh + TEN;
    u16* Vt  = Kl + TEN;                          // [B][DP][N] transposed V
    u16* Wth = Vt + TEN;
    u16* Wtl = Wth + (size_t)3 * DP * DP;

    hipLaunchKernelGGL(wprep, dim3(3), dim3(256), 0, stream, Wq, Wk, Wv, Wth, Wtl);
    hipLaunchKernelGGL(proj_kernel, dim3((B_ * N_) / 64, 3), dim3(256), 0, stream,
                       x1, x2, Wth, Wtl, Qh, Ql, Kh, Kl, Vt);
    hipLaunchKernelGGL(attn_kernel, dim3(N_ / QB, B_), dim3(512), 0, stream,
                       Qh, Ql, Kh, Kl, Vt, mask, outp, attnw);
}

// Round 2
// 384.112 us; speedup vs baseline: 1.0496x; 1.0496x over previous
//
#include <hip/hip_runtime.h>
#include <stdint.h>

#define B_ 8
#define N_ 2048
#define D_ 120
#define DP 128          // D padded to 128 (k-dim of MFMA)
#define QB 16           // q rows per block in attention kernel

typedef __attribute__((ext_vector_type(8))) short short8;
typedef __attribute__((ext_vector_type(4))) float f32x4;
typedef __attribute__((ext_vector_type(2))) float f32x2;
typedef __attribute__((ext_vector_type(4))) float float4v;
typedef __attribute__((ext_vector_type(4))) unsigned int u32x4;
typedef unsigned short u16;
typedef unsigned int u32;

// f32 -> bf16 (RNE) and back, bit-level (all values finite here)
__device__ __forceinline__ u16 f2bf(float f){
    union { float f; uint32_t u; } v; v.f = f;
    uint32_t u = v.u;
    return (u16)((u + 0x7fffu + ((u >> 16) & 1u)) >> 16);
}
__device__ __forceinline__ float bf2f(u16 h){
    union { uint32_t u; float f; } v; v.u = ((uint32_t)h) << 16; return v.f;
}

__device__ __forceinline__ f32x4 mfma16(short8 a, short8 b, f32x4 c){
    return __builtin_amdgcn_mfma_f32_16x16x32_bf16(a, b, c, 0, 0, 0);
}

// ---------------------------------------------------------------------------
// Kernel 0: transpose + split weights. Wt[c][d] (bf16 hi/lo), zero-padded to
// 128x128. Scale 1/sqrt(D) folded into W_query.
// ---------------------------------------------------------------------------
__global__ void wprep(const float* __restrict__ Wq, const float* __restrict__ Wk,
                      const float* __restrict__ Wv,
                      u16* __restrict__ Wth, u16* __restrict__ Wtl){
    int p = blockIdx.x;
    const float* W = (p == 0) ? Wq : (p == 1 ? Wk : Wv);
    float scale = (p == 0) ? 0.09128709291752768f : 1.0f;  // 1/sqrt(120)
    for (int idx = threadIdx.x; idx < DP * DP; idx += blockDim.x){
        int c = idx & (DP - 1);
        int d = idx >> 7;
        float w = (c < D_ && d < D_) ? W[d * D_ + c] * scale : 0.f;
        u16 hi = f2bf(w);
        Wth[p * DP * DP + c * DP + d] = hi;
        Wtl[p * DP * DP + c * DP + d] = f2bf(w - bf2f(hi));
    }
}

// ---------------------------------------------------------------------------
// Kernel 0b: mask -> bitmask. One wave per (b, n1) row; 32 ballot iterations
// compress 2048 int32 to 64 u32 words. Fully coalesced 256B/instr reads.
// ---------------------------------------------------------------------------
__global__ __launch_bounds__(256)
void maskprep(const int* __restrict__ mask, u32* __restrict__ bits){
    int wid  = (blockIdx.x * 256 + threadIdx.x) >> 6;   // global wave id = row
    int lane = threadIdx.x & 63;
    long base = (long)wid * N_;
    u32 myw = 0;
    #pragma unroll
    for (int it = 0; it < 32; ++it){
        int v = mask[base + it * 64 + lane];
        unsigned long long bb = __ballot(v != 0);
        if ((lane >> 1) == it)
            myw = (lane & 1) ? (u32)(bb >> 32) : (u32)bb;
    }
    bits[((long)wid << 6) + lane] = myw;
}

// ---------------------------------------------------------------------------
// Kernel 1: projections via 3-term split-bf16 MFMA.
// ---------------------------------------------------------------------------
__global__ __launch_bounds__(256, 4)
void proj_kernel(const float* __restrict__ x1, const float* __restrict__ x2,
                 const u16* __restrict__ Wth, const u16* __restrict__ Wtl,
                 u16* __restrict__ Qh, u16* __restrict__ Ql,
                 u16* __restrict__ Kh, u16* __restrict__ Kl,
                 u16* __restrict__ Vt){
    int p    = blockIdx.y;
    const float* x = (p == 0) ? x1 : x2;
    int wave = threadIdx.x >> 6, lane = threadIdx.x & 63;
    int g = lane >> 4, ln = lane & 15;
    long arow = (long)blockIdx.x * 64 + wave * 16 + ln;     // A row (M index)

    // A fragments: lane holds row (lane&15), k = 8*(lane>>4)+j
    short8 ah[4], al[4];
    #pragma unroll
    for (int ks = 0; ks < 4; ++ks){
        int d0 = ks * 32 + g * 8;
        float xv[8];
        if (d0 < D_){
            float4v v0 = *(const float4v*)(x + arow * D_ + d0);
            float4v v1 = *(const float4v*)(x + arow * D_ + d0 + 4);
            xv[0]=v0[0]; xv[1]=v0[1]; xv[2]=v0[2]; xv[3]=v0[3];
            xv[4]=v1[0]; xv[5]=v1[1]; xv[6]=v1[2]; xv[7]=v1[3];
        } else {
            #pragma unroll
            for (int j = 0; j < 8; ++j) xv[j] = 0.f;
        }
        short8 h, l;
        #pragma unroll
        for (int j = 0; j < 8; ++j){
            u16 hb = f2bf(xv[j]);
            h[j] = (short)hb;
            l[j] = (short)f2bf(xv[j] - bf2f(hb));
        }
        ah[ks] = h; al[ks] = l;
    }

    const u16* wh = Wth + p * DP * DP;
    const u16* wl = Wtl + p * DP * DP;
    f32x4 acc[8];
    #pragma unroll
    for (int cf = 0; cf < 8; ++cf){
        f32x4 a = {0.f, 0.f, 0.f, 0.f};
        #pragma unroll
        for (int ks = 0; ks < 4; ++ks){
            short8 bh = *(const short8*)(wh + (cf * 16 + ln) * DP + ks * 32 + g * 8);
            short8 bl = *(const short8*)(wl + (cf * 16 + ln) * DP + ks * 32 + g * 8);
            a = mfma16(ah[ks], bh, a);
            a = mfma16(ah[ks], bl, a);
            a = mfma16(al[ks], bh, a);
        }
        acc[cf] = a;
    }

    // C/D layout: col = lane&15, row = 4*(lane>>4)+i
    #pragma unroll
    for (int cf = 0; cf < 8; ++cf){
        #pragma unroll
        for (int i = 0; i < 4; ++i){
            long orow = (long)blockIdx.x * 64 + wave * 16 + g * 4 + i;
            int  c    = cf * 16 + ln;
            float v   = acc[cf][i];
            if (p == 0){
                u16 hb = f2bf(v);
                Qh[orow * DP + c] = hb;
                Ql[orow * DP + c] = f2bf(v - bf2f(hb));
            } else if (p == 1){
                u16 hb = f2bf(v);
                Kh[orow * DP + c] = hb;
                Kl[orow * DP + c] = f2bf(v - bf2f(hb));
            } else {
                long bb = orow >> 11, n = orow & 2047;
                Vt[(bb * DP + c) * N_ + n] = f2bf(v);
            }
        }
    }
}

// ---------------------------------------------------------------------------
// Kernel 2: fused scores + softmax + attn-weight store + PV.
// Grid (128, 8): block = (batch, 16 q-rows). 8 waves; wave w owns the 16x256
// column slice [w*256, w*256+256). Scores: sc[16] f32x4 = 64 VGPR.
// P-transpose via wave-private LDS tile (no barrier); attnw stored dwordx4;
// PV fed from registers (pa[8]); cross-wave output reduce via LDS atomics.
// ---------------------------------------------------------------------------
__global__ __launch_bounds__(512, 4)
void attn_kernel(const u16* __restrict__ Qh, const u16* __restrict__ Ql,
                 const u16* __restrict__ Kh, const u16* __restrict__ Kl,
                 const u16* __restrict__ Vt, const u32* __restrict__ bits,
                 float* __restrict__ outp, float* __restrict__ attnw){
    __shared__ float tile[8][16 * 34];   // per-wave transpose tiles (17408 B)
    __shared__ float red0[8][16];        // row-max partials
    __shared__ float red1[8][16];        // row-sum partials
    __shared__ float outred[16 * 128];   // 8 KB output reduce

    int b  = blockIdx.y;
    int q0 = blockIdx.x * QB;
    int w  = threadIdx.x >> 6, lane = threadIdx.x & 63;
    int g  = lane >> 4, ln = lane & 15;
    long rowbase = (long)b * N_ + q0;

    // zero output-reduce buffer early (softmax syncs cover visibility)
    #pragma unroll
    for (int idx = threadIdx.x; idx < 16 * 128; idx += 512) outred[idx] = 0.f;

    // ---- Q A-fragments ----
    short8 ah[4], al[4];
    #pragma unroll
    for (int ks = 0; ks < 4; ++ks){
        ah[ks] = *(const short8*)(Qh + (rowbase + ln) * DP + ks * 32 + g * 8);
        al[ks] = *(const short8*)(Ql + (rowbase + ln) * DP + ks * 32 + g * 8);
    }

    // ---- scores: S = Qs @ K^T (3-term split) ----
    f32x4 sc[16];
    #pragma unroll
    for (int cf = 0; cf < 16; ++cf){
        long krow = (long)b * N_ + w * 256 + cf * 16 + ln;
        const u16* kh = Kh + krow * DP;
        const u16* kl = Kl + krow * DP;
        f32x4 a = {0.f, 0.f, 0.f, 0.f};
        #pragma unroll
        for (int ks = 0; ks < 4; ++ks){
            short8 bh = *(const short8*)(kh + ks * 32 + g * 8);
            short8 bl = *(const short8*)(kl + ks * 32 + g * 8);
            a = mfma16(ah[ks], bh, a);
            a = mfma16(ah[ks], bl, a);
            a = mfma16(al[ks], bh, a);
        }
        sc[cf] = a;
    }

    // ---- mask via bitmask (4 MB, L2/L3-resident) ----
    const u32* bb = bits + rowbase * 64 + w * 8;
    #pragma unroll
    for (int i = 0; i < 4; ++i){
        const u32* rp = bb + (long)(g * 4 + i) * 64;
        u32x4 m0 = *(const u32x4*)rp;
        u32x4 m1 = *(const u32x4*)(rp + 4);
        u32 mw[8] = {m0[0], m0[1], m0[2], m0[3], m1[0], m1[1], m1[2], m1[3]};
        #pragma unroll
        for (int cf = 0; cf < 16; ++cf){
            u32 word = mw[cf >> 1];
            int bit  = (cf & 1) * 16 + ln;
            if (!((word >> bit) & 1u)) sc[cf][i] = -__builtin_inff();
        }
    }

    // ---- row max: in-wave over 16 cols x 16 frags, then cross-wave ----
    float mx[4];
    #pragma unroll
    for (int i = 0; i < 4; ++i){
        float m = sc[0][i];
        #pragma unroll
        for (int cf = 1; cf < 16; ++cf) m = fmaxf(m, sc[cf][i]);
        #pragma unroll
        for (int s = 1; s < 16; s <<= 1) m = fmaxf(m, __shfl_xor(m, s, 64));
        mx[i] = m;
    }
    if (ln == 0){
        #pragma unroll
        for (int i = 0; i < 4; ++i) red0[w][g * 4 + i] = mx[i];
    }
    __syncthreads();
    float fm[4];
    #pragma unroll
    for (int i = 0; i < 4; ++i){
        int r = g * 4 + i;
        float m = red0[0][r];
        #pragma unroll
        for (int w2 = 1; w2 < 8; ++w2) m = fmaxf(m, red0[w2][r]);
        fm[i] = m;
    }

    // ---- exp + row sum ----
    float sm[4] = {0.f, 0.f, 0.f, 0.f};
    #pragma unroll
    for (int cf = 0; cf < 16; ++cf){
        #pragma unroll
        for (int i = 0; i < 4; ++i){
            float e = __expf(sc[cf][i] - fm[i]);
            sc[cf][i] = e;
            sm[i] += e;
        }
    }
    #pragma unroll
    for (int i = 0; i < 4; ++i){
        float s = sm[i];
        #pragma unroll
        for (int sft = 1; sft < 16; sft <<= 1) s += __shfl_xor(s, sft, 64);
        sm[i] = s;
    }
    if (ln == 0){
        #pragma unroll
        for (int i = 0; i < 4; ++i) red1[w][g * 4 + i] = sm[i];
    }
    __syncthreads();
    float inv[4];
    #pragma unroll
    for (int i = 0; i < 4; ++i){
        int r = g * 4 + i;
        float s = red1[0][r];
        #pragma unroll
        for (int w2 = 1; w2 < 8; ++w2) s += red1[w2][r];
        inv[i] = 1.f / s;
    }

    // ---- per-32-col chunks: LDS transpose -> vectorized attnw store + pa ----
    float* mytile = &tile[w][0];
    short8 pa[8];
    #pragma unroll
    for (int mc = 0; mc < 8; ++mc){
        // write C-layout (normalized) into wave-private tile [16][34]
        #pragma unroll
        for (int t = 0; t < 2; ++t){
            #pragma unroll
            for (int i = 0; i < 4; ++i)
                mytile[(g * 4 + i) * 34 + t * 16 + ln] = sc[mc * 2 + t][i] * inv[i];
        }
        // read A-layout: row ln, 8 consecutive cols at g*8 (b64 reads)
        float p[8];
        #pragma unroll
        for (int k = 0; k < 4; ++k){
            f32x2 t2 = *(const f32x2*)&mytile[ln * 34 + g * 8 + 2 * k];
            p[2 * k] = t2[0]; p[2 * k + 1] = t2[1];
        }
        // vectorized attnw store (16B x2 per lane)
        float* ap = attnw + (rowbase + ln) * N_ + w * 256 + mc * 32 + g * 8;
        f32x4 s0 = {p[0], p[1], p[2], p[3]};
        f32x4 s1 = {p[4], p[5], p[6], p[7]};
        *(f32x4*)ap       = s0;
        *(f32x4*)(ap + 4) = s1;
        // A-fragment for PV
        short8 t8;
        #pragma unroll
        for (int j = 0; j < 8; ++j) t8[j] = (short)f2bf(p[j]);
        pa[mc] = t8;
    }

    // ---- PV: out += P @ V ----
    f32x4 oacc[8];
    #pragma unroll
    for (int e = 0; e < 8; ++e) oacc[e] = (f32x4){0.f, 0.f, 0.f, 0.f};
    #pragma unroll
    for (int mc = 0; mc < 8; ++mc){
        const u16* vbase = Vt + ((long)b * DP + ln) * N_ + w * 256 + mc * 32 + g * 8;
        #pragma unroll
        for (int e = 0; e < 8; ++e){
            short8 vb = *(const short8*)(vbase + (long)e * 16 * N_);
            oacc[e] = mfma16(pa[mc], vb, oacc[e]);
        }
    }

    // ---- cross-wave reduce (LDS float atomics) + store output ----
    __syncthreads();   // ensure all zeroing visible & phases aligned
    #pragma unroll
    for (int e = 0; e < 8; ++e){
        #pragma unroll
        for (int i = 0; i < 4; ++i)
            atomicAdd(&outred[(g * 4 + i) * 128 + e * 16 + ln], oacc[e][i]);
    }
    __syncthreads();
    {
        int t4  = threadIdx.x * 4;
        int row = t4 >> 7;
        int e0  = t4 & 127;
        if (e0 <= 116){
            f32x4 v = {outred[row * 128 + e0],     outred[row * 128 + e0 + 1],
                       outred[row * 128 + e0 + 2], outred[row * 128 + e0 + 3]};
            *(f32x4*)(outp + (rowbase + row) * D_ + e0) = v;
        }
    }
}

// ---------------------------------------------------------------------------
extern "C" void kernel_launch(void* const* d_in, const int* in_sizes, int n_in,
                              void* d_out, int out_size, void* d_ws, size_t ws_size,
                              hipStream_t stream){
    const float* x1   = (const float*)d_in[0];
    const float* x2   = (const float*)d_in[1];
    const int*   mask = (const int*)d_in[2];
    const float* Wq   = (const float*)d_in[3];
    const float* Wk   = (const float*)d_in[4];
    const float* Wv   = (const float*)d_in[5];

    float* outp  = (float*)d_out;
    float* attnw = outp + (size_t)B_ * N_ * D_;   // outputs concatenated flat

    // workspace carve: bits (4MB) + 5 x 4MB bf16 tensors + split weights
    const size_t TEN = (size_t)B_ * N_ * DP;      // 2,097,152
    u32* bits = (u32*)d_ws;                       // B*N*64 u32 = 4 MB
    u16* Qh   = (u16*)(bits + (size_t)B_ * N_ * 64);
    u16* Ql   = Qh + TEN;
    u16* Kh   = Ql + TEN;
    u16* Kl   = Kh + TEN;
    u16* Vt   = Kl + TEN;                         // [B][DP][N] transposed V
    u16* Wth  = Vt + TEN;
    u16* Wtl  = Wth + (size_t)3 * DP * DP;

    hipLaunchKernelGGL(wprep, dim3(3), dim3(256), 0, stream, Wq, Wk, Wv, Wth, Wtl);
    hipLaunchKernelGGL(maskprep, dim3((B_ * N_) / 4), dim3(256), 0, stream, mask, bits);
    hipLaunchKernelGGL(proj_kernel, dim3((B_ * N_) / 64, 3), dim3(256), 0, stream,
                       x1, x2, Wth, Wtl, Qh, Ql, Kh, Kl, Vt);
    hipLaunchKernelGGL(attn_kernel, dim3(N_ / QB, B_), dim3(512), 0, stream,
                       Qh, Ql, Kh, Kl, Vt, bits, outp, attnw);
}